// Round 1
// 888.712 us; speedup vs baseline: 1.0387x; 1.0387x over previous
//
#include <hip/hip_runtime.h>
#include <stdint.h>

// Bahdanau attention, MI355X. Round 3.
// k_score rewritten as T3 "minimum 2-phase" pipeline: BM=128 x BN=512(full),
// BK=32, 8 waves, double-buffered LDS, stage(ks+1) issued BEFORE mfma(ks),
// single __syncthreads per K-step (vmcnt(0) drain aged through MFMA phase).
// Swizzled chunk layout identical to round 2 (conflict-free b128 frag reads).
// k_ctx: partial-buffer + reduce (no atomics) when ws allows; atomic fallback.

typedef float  f32x4 __attribute__((ext_vector_type(4)));
typedef short  s16x8 __attribute__((ext_vector_type(8)));
typedef unsigned short u16x8 __attribute__((ext_vector_type(8)));

#define AS_GLB __attribute__((address_space(1)))
#define AS_LDS __attribute__((address_space(3)))

__device__ __forceinline__ unsigned short f2bf(float f) {
    unsigned int u = __float_as_uint(f);
    u += 0x7fffu + ((u >> 16) & 1u);          // RNE
    return (unsigned short)(u >> 16);
}

__device__ __forceinline__ float fast_tanh(float x) {
    // 1 - 2/(e^{2x}+1); saturates correctly at +/-inf, ~1e-6 abs error
    return 1.0f - 2.0f / (__expf(2.0f * x) + 1.0f);
}

// ---------- K1a: tiled transpose + bf16 cast of W1 -> w1t[n][k] ----------
__global__ __launch_bounds__(256) void k_w1t(const float* __restrict__ W1,
                                             unsigned short* __restrict__ w1t) {
    __shared__ float tile[64][65];
    const int k0 = blockIdx.x * 64;
    const int n0 = blockIdx.y * 64;
    const int t = threadIdx.x, ty = t >> 6, tx = t & 63;
    #pragma unroll
    for (int i = ty; i < 64; i += 4)
        tile[i][tx] = W1[(size_t)(k0 + i) * 512 + n0 + tx];
    __syncthreads();
    #pragma unroll
    for (int i = ty; i < 64; i += 4)
        w1t[(size_t)(n0 + i) * 2048 + k0 + tx] = f2bf(tile[tx][i]);
}

// ---------- K1b: proj_h = hidden @ W2 + b2 (grid 64x4) ----------
__global__ __launch_bounds__(256) void k_projh(const float* __restrict__ hs,
                                               const float* __restrict__ W2,
                                               const float* __restrict__ b2,
                                               float* __restrict__ ph) {
    __shared__ float hsm[512];
    __shared__ float part[256];
    const int b = blockIdx.x, c0 = blockIdx.y * 128, t = threadIdx.x;
    hsm[t]       = hs[b * 512 + t];
    hsm[t + 256] = hs[b * 512 + t + 256];
    __syncthreads();
    const int j = c0 + (t & 127), half = t >> 7;
    float s = 0.f;
    const float* wp = W2 + (size_t)(half * 256) * 512 + j;
    const float* hp = hsm + half * 256;
    #pragma unroll 8
    for (int i = 0; i < 256; ++i) s += hp[i] * wp[(size_t)i * 512];
    part[t] = s;
    __syncthreads();
    if (t < 128) ph[b * 512 + j] = part[t] + part[t + 128] + b2[j];
}

// ---------- K2: fused GEMM + tanh + V-dot -> score ----------
// grid 512 (M/128), 512 threads = 8 waves (2 row-groups x 4 col-groups).
// Wave (wrow,wcol) owns rows [wrow*64,+64), cols [wcol*128,+128).
// LDS chunk layout (16B chunks): slot(row, c) = row*4 + (c ^ ((row>>1)&3))
// Double-buffered; per K-step: stage(ks+1) -> ds_read(ks) -> 32 MFMA -> barrier.
__global__ __launch_bounds__(512, 2) void k_score(const float* __restrict__ feat,
                                                  const unsigned short* __restrict__ w1t,
                                                  const float* __restrict__ b1,
                                                  const float* __restrict__ ph,
                                                  const float* __restrict__ V,
                                                  float* __restrict__ score) {
    __shared__ __align__(16) unsigned short As[2][128 * 32];   // 2 x 8 KiB, swizzled
    __shared__ __align__(16) unsigned short Bs[2][512 * 32];   // 2 x 32 KiB, swizzled
    __shared__ float red[8][64];

    const int tid  = threadIdx.x;
    const int wave = tid >> 6, lane = tid & 63;
    const int quad = lane >> 4, l15 = lane & 15;
    const int wrow = wave >> 2, wcol = wave & 3;
    const int m0 = blockIdx.x * 128;
    const int bb = m0 >> 10;                                 // batch (128 rows never cross batch)

    // A staging: 512 chunks (m:128 x c:4), one per thread
    const int am = tid >> 2, ac = tid & 3;
    const float* aptr = feat + (size_t)(m0 + am) * 2048 + ac * 8;
    const int asl = (am * 4 + (ac ^ ((am >> 1) & 3))) * 8;   // ushort offset

    // B staging: 4 reps/thread; wave sw covers n in [sw*64, sw*64+64)
    //   rep r: n = sw*64 + r*16 + (lane>>2), c = (lane&3)^((lane>>3)&3)
    //   dest slot = sw*256 + r*64 + lane  ==  n*4 + (c ^ ((n>>1)&3))   [verified]
    const int bn0 = wave * 64 + (lane >> 2);
    const int bc  = (lane & 3) ^ ((lane >> 3) & 3);
    const unsigned short* bptr = w1t + (size_t)bn0 * 2048 + bc * 8;

    f32x4 acc[4][8];
    const f32x4 zero = {0.f, 0.f, 0.f, 0.f};
    #pragma unroll
    for (int i = 0; i < 4; ++i)
        #pragma unroll
        for (int j = 0; j < 8; ++j) acc[i][j] = zero;

    // ---- prologue: stage tile 0 into buf 0, prefetch A(1) into regs ----
    f32x4 a0 = *(const f32x4*)aptr;
    f32x4 a1 = *(const f32x4*)(aptr + 4);
    {
        u16x8 aw;
        aw[0] = f2bf(a0.x); aw[1] = f2bf(a0.y); aw[2] = f2bf(a0.z); aw[3] = f2bf(a0.w);
        aw[4] = f2bf(a1.x); aw[5] = f2bf(a1.y); aw[6] = f2bf(a1.z); aw[7] = f2bf(a1.w);
        *(u16x8*)(&As[0][asl]) = aw;
        #pragma unroll
        for (int r = 0; r < 4; ++r) {
            __builtin_amdgcn_global_load_lds((const AS_GLB uint32_t*)(bptr + (size_t)r * 16 * 2048),
                                             (AS_LDS uint32_t*)(&Bs[0][(wave * 256 + r * 64) * 8]),
                                             16, 0, 0);
        }
        a0 = *(const f32x4*)(aptr + 32);
        a1 = *(const f32x4*)(aptr + 36);
    }
    __syncthreads();                                         // tile 0 staged, A(1) in regs

    for (int ks = 0; ks < 64; ++ks) {
        const int cur = ks & 1, nxt = cur ^ 1;

        if (ks < 63) {                                       // ---- stage tile ks+1 EARLY ----
            u16x8 aw;
            aw[0] = f2bf(a0.x); aw[1] = f2bf(a0.y); aw[2] = f2bf(a0.z); aw[3] = f2bf(a0.w);
            aw[4] = f2bf(a1.x); aw[5] = f2bf(a1.y); aw[6] = f2bf(a1.z); aw[7] = f2bf(a1.w);
            *(u16x8*)(&As[nxt][asl]) = aw;                   // ds_write_b128
            const unsigned short* g = bptr + (ks + 1) * 32;
            #pragma unroll
            for (int r = 0; r < 4; ++r) {
                __builtin_amdgcn_global_load_lds((const AS_GLB uint32_t*)(g + (size_t)r * 16 * 2048),
                                                 (AS_LDS uint32_t*)(&Bs[nxt][(wave * 256 + r * 64) * 8]),
                                                 16, 0, 0);
            }
            if (ks < 62) {                                   // prefetch A(ks+2) f32 regs
                const float* ap = aptr + (ks + 2) * 32;
                a0 = *(const f32x4*)ap;
                a1 = *(const f32x4*)(ap + 4);
            }
        }

        // ---- compute tile ks from buf[cur] ----
        s16x8 af[4], bfr[8];
        #pragma unroll
        for (int i = 0; i < 4; ++i) {
            const int m = wrow * 64 + i * 16 + l15;
            af[i] = *(const s16x8*)(&As[cur][(m * 4 + (quad ^ ((m >> 1) & 3))) * 8]);
        }
        #pragma unroll
        for (int j = 0; j < 8; ++j) {
            const int n = wcol * 128 + j * 16 + l15;
            bfr[j] = *(const s16x8*)(&Bs[cur][(n * 4 + (quad ^ ((n >> 1) & 3))) * 8]);
        }
        #pragma unroll
        for (int i = 0; i < 4; ++i)
            #pragma unroll
            for (int j = 0; j < 8; ++j)
                acc[i][j] = __builtin_amdgcn_mfma_f32_16x16x32_bf16(af[i], bfr[j], acc[i][j], 0, 0, 0);

        __syncthreads();   // vmcnt(0)+lgkmcnt(0): glds(ks+1) aged through reads+MFMA
    }

    // epilogue: rows m = wrow*64 + i*16 + quad*4 + r, cols n = wcol*128 + j*16 + l15
    float ls[4][4];
    #pragma unroll
    for (int i = 0; i < 4; ++i)
        #pragma unroll
        for (int r = 0; r < 4; ++r) ls[i][r] = 0.f;
    #pragma unroll
    for (int j = 0; j < 8; ++j) {
        const int n = wcol * 128 + j * 16 + l15;
        const float bias = b1[n] + ph[bb * 512 + n];
        const float vj = V[n];
        #pragma unroll
        for (int i = 0; i < 4; ++i)
            #pragma unroll
            for (int r = 0; r < 4; ++r)
                ls[i][r] += vj * fast_tanh(acc[i][j][r] + bias);
    }
    #pragma unroll
    for (int m = 1; m < 16; m <<= 1)
        #pragma unroll
        for (int i = 0; i < 4; ++i)
            #pragma unroll
            for (int r = 0; r < 4; ++r)
                ls[i][r] += __shfl_xor(ls[i][r], m, 64);
    if (l15 == 0) {
        #pragma unroll
        for (int i = 0; i < 4; ++i)
            #pragma unroll
            for (int r = 0; r < 4; ++r)
                red[wave][i * 16 + quad * 4 + r] = ls[i][r];
    }
    __syncthreads();
    if (tid < 128) {
        const int wr = tid >> 6, x = tid & 63;
        score[m0 + wr * 64 + x] = red[wr * 4 + 0][x] + red[wr * 4 + 1][x]
                                + red[wr * 4 + 2][x] + red[wr * 4 + 3][x];
    }
}

// ---------- K3: softmax over L ----------
__global__ __launch_bounds__(256) void k_softmax(const float* __restrict__ score,
                                                 float* __restrict__ wout,
                                                 float* __restrict__ ctx,
                                                 int zero_ctx) {
    __shared__ float sred[4];
    const int b = blockIdx.x, t = threadIdx.x;
    const int wave = t >> 6, lane = t & 63;
    float s[4];
    #pragma unroll
    for (int i = 0; i < 4; ++i) s[i] = score[b * 1024 + t + i * 256];
    float mx = fmaxf(fmaxf(s[0], s[1]), fmaxf(s[2], s[3]));
    #pragma unroll
    for (int m = 1; m < 64; m <<= 1) mx = fmaxf(mx, __shfl_xor(mx, m, 64));
    if (lane == 0) sred[wave] = mx;
    __syncthreads();
    mx = fmaxf(fmaxf(sred[0], sred[1]), fmaxf(sred[2], sred[3]));
    float e[4], sum = 0.f;
    #pragma unroll
    for (int i = 0; i < 4; ++i) { e[i] = __expf(s[i] - mx); sum += e[i]; }
    #pragma unroll
    for (int m = 1; m < 64; m <<= 1) sum += __shfl_xor(sum, m, 64);
    __syncthreads();
    if (lane == 0) sred[wave] = sum;
    __syncthreads();
    const float inv = 1.0f / (sred[0] + sred[1] + sred[2] + sred[3]);
    #pragma unroll
    for (int i = 0; i < 4; ++i) wout[b * 1024 + t + i * 256] = e[i] * inv;
    if (zero_ctx) {
        #pragma unroll
        for (int i = 0; i < 8; ++i) ctx[b * 2048 + t + i * 256] = 0.f;
    }
}

// ---------- K4: context partials (no atomics) ----------
__global__ __launch_bounds__(256) void k_ctx_part(const float* __restrict__ feat,
                                                  const float* __restrict__ wgt,
                                                  float* __restrict__ part) {
    __shared__ float wl[128];
    const int b = blockIdx.x, lc = blockIdx.y, t = threadIdx.x;
    if (t < 128) wl[t] = wgt[b * 1024 + lc * 128 + t];
    __syncthreads();
    const float* fp = feat + ((size_t)b * 1024 + (size_t)lc * 128) * 2048 + t * 8;
    f32x4 a0 = {0.f, 0.f, 0.f, 0.f}, a1 = {0.f, 0.f, 0.f, 0.f};
    #pragma unroll 4
    for (int l = 0; l < 128; ++l) {
        const f32x4 f0 = *(const f32x4*)(fp + (size_t)l * 2048);
        const f32x4 f1 = *(const f32x4*)(fp + (size_t)l * 2048 + 4);
        const float w = wl[l];
        a0 += w * f0;
        a1 += w * f1;
    }
    float* pp = part + ((size_t)(b * 8 + lc)) * 2048 + t * 8;
    *(f32x4*)pp = a0;
    *(f32x4*)(pp + 4) = a1;
}

__global__ __launch_bounds__(256) void k_ctx_red(const float* __restrict__ part,
                                                 float* __restrict__ ctx) {
    const int b = blockIdx.x, t = threadIdx.x;
    const float* pp = part + (size_t)b * 8 * 2048 + t * 8;
    f32x4 s0 = {0.f, 0.f, 0.f, 0.f}, s1 = {0.f, 0.f, 0.f, 0.f};
    #pragma unroll
    for (int r = 0; r < 8; ++r) {
        s0 += *(const f32x4*)(pp + (size_t)r * 2048);
        s1 += *(const f32x4*)(pp + (size_t)r * 2048 + 4);
    }
    float* cp = ctx + b * 2048 + t * 8;
    *(f32x4*)cp = s0;
    *(f32x4*)(cp + 4) = s1;
}

// ---------- K4 fallback: atomics (if ws too small for partials) ----------
__global__ __launch_bounds__(256) void k_ctx_atomic(const float* __restrict__ feat,
                                                    const float* __restrict__ wgt,
                                                    float* __restrict__ ctx) {
    __shared__ float wl[128];
    const int b = blockIdx.x, lc = blockIdx.y, t = threadIdx.x;
    if (t < 128) wl[t] = wgt[b * 1024 + lc * 128 + t];
    __syncthreads();
    const float* fp = feat + ((size_t)b * 1024 + (size_t)lc * 128) * 2048 + t * 8;
    f32x4 a0 = {0.f, 0.f, 0.f, 0.f}, a1 = {0.f, 0.f, 0.f, 0.f};
    #pragma unroll 4
    for (int l = 0; l < 128; ++l) {
        const f32x4 f0 = *(const f32x4*)(fp + (size_t)l * 2048);
        const f32x4 f1 = *(const f32x4*)(fp + (size_t)l * 2048 + 4);
        const float w = wl[l];
        a0 += w * f0;
        a1 += w * f1;
    }
    float* cp = ctx + b * 2048 + t * 8;
    atomicAdd(cp + 0, a0.x); atomicAdd(cp + 1, a0.y);
    atomicAdd(cp + 2, a0.z); atomicAdd(cp + 3, a0.w);
    atomicAdd(cp + 4, a1.x); atomicAdd(cp + 5, a1.y);
    atomicAdd(cp + 6, a1.z); atomicAdd(cp + 7, a1.w);
}

extern "C" void kernel_launch(void* const* d_in, const int* in_sizes, int n_in,
                              void* d_out, int out_size, void* d_ws, size_t ws_size,
                              hipStream_t stream) {
    const float* feat = (const float*)d_in[0];   // [64][1024][2048]
    const float* hs   = (const float*)d_in[1];   // [64][512]
    const float* W1   = (const float*)d_in[2];   // [2048][512]
    const float* b1   = (const float*)d_in[3];   // [512]
    const float* W2   = (const float*)d_in[4];   // [512][512]
    const float* b2   = (const float*)d_in[5];   // [512]
    const float* V    = (const float*)d_in[6];   // [512]
    // d_in[7] = bv: cancels in softmax, score not an output -> unused

    const size_t OFF_PH    = 2u * 1024 * 1024;
    const size_t OFF_SCORE = OFF_PH + 128u * 1024;
    const size_t OFF_PART  = OFF_SCORE + 256u * 1024;
    const size_t NEED_PART = OFF_PART + (size_t)64 * 8 * 2048 * 4;

    unsigned short* w1t = (unsigned short*)d_ws;
    float* ph    = (float*)((char*)d_ws + OFF_PH);
    float* score = (float*)((char*)d_ws + OFF_SCORE);
    float* part  = (float*)((char*)d_ws + OFF_PART);

    float* ctx  = (float*)d_out;          // [64][2048]
    float* wout = ctx + 64 * 2048;        // [64][1024][1]

    const int use_part = (ws_size >= NEED_PART) ? 1 : 0;

    k_w1t    <<<dim3(32, 8), 256, 0, stream>>>(W1, w1t);
    k_projh  <<<dim3(64, 4), 256, 0, stream>>>(hs, W2, b2, ph);
    k_score  <<<512,         512, 0, stream>>>(feat, w1t, b1, ph, V, score);
    k_softmax<<<64,          256, 0, stream>>>(score, wout, ctx, use_part ? 0 : 1);
    if (use_part) {
        k_ctx_part<<<dim3(64, 8), 256, 0, stream>>>(feat, wout, part);
        k_ctx_red <<<64,          256, 0, stream>>>(part, ctx);
    } else {
        k_ctx_atomic<<<dim3(64, 8), 256, 0, stream>>>(feat, wout, ctx);
    }
}